// Round 6
// baseline (305.837 us; speedup 1.0000x reference)
//
#include <hip/hip_runtime.h>
#include <cstdint>
#include <cstddef>

#define DIN 1280
#define DOUT 3840
#define NEXP 6
#define RANK 16
#define TOKENS 16384
#define KPAD 1408   // 1280 x + 16 shared + 96 routed + 16 zero pad
#define NLOW 128    // padded low-rank cols (112 valid)

typedef __bf16 bf16x8 __attribute__((ext_vector_type(8)));
typedef float f32x4 __attribute__((ext_vector_type(4)));
typedef unsigned short u16x8 __attribute__((ext_vector_type(8)));

__device__ __forceinline__ unsigned short f2bf(float f) {
    unsigned u = __builtin_bit_cast(unsigned, f);
    u += 0x7fff + ((u >> 16) & 1);   // RNE
    return (unsigned short)(u >> 16);
}

__device__ __forceinline__ void async_load16(void* lds, const void* g) {
    __builtin_amdgcn_global_load_lds(
        (const __attribute__((address_space(1))) unsigned int*)g,
        (__attribute__((address_space(3))) unsigned int*)lds, 16, 0, 0);
}

// Build WcatT [DOUT][KPAD] bf16: rows n, cols k. k<1280: base_w[k][n];
// 1280..1295: shared_w2[k-1280][n]; 1296..1391: routed_w2 flat[k-1296][n]; else 0.
__global__ void prep_w2t(const float* __restrict__ base_w,
                         const float* __restrict__ shared_w2,
                         const float* __restrict__ routed_w2,
                         unsigned short* __restrict__ WT) {
    __shared__ unsigned short tile[32][33];
    int k0 = blockIdx.x * 32, n0 = blockIdx.y * 32;
    int tx = threadIdx.x, ty = threadIdx.y;
#pragma unroll
    for (int j = 0; j < 4; j++) {
        int k = k0 + ty + j * 8;
        int n = n0 + tx;
        float v;
        if (k < DIN)            v = base_w[(size_t)k * DOUT + n];
        else if (k < DIN + 16)  v = shared_w2[(size_t)(k - DIN) * DOUT + n];
        else if (k < DIN + 112) v = routed_w2[(size_t)(k - DIN - 16) * DOUT + n];
        else                    v = 0.f;
        tile[ty + j * 8][tx] = f2bf(v);
    }
    __syncthreads();
#pragma unroll
    for (int j = 0; j < 4; j++) {
        int n = n0 + ty + j * 8;
        int k = k0 + tx;
        WT[(size_t)n * KPAD + k] = tile[tx][ty + j * 8];
    }
}

// Build W1catT [NLOW][DIN] bf16: row n<16: shared_w1[:,n]; 16..111: routed_w1[e][:,r]; else 0.
__global__ void prep_w1t(const float* __restrict__ shared_w1,
                         const float* __restrict__ routed_w1,
                         unsigned short* __restrict__ W1T) {
    __shared__ unsigned short tile[32][33];
    int k0 = blockIdx.x * 32, n0 = blockIdx.y * 32;
    int tx = threadIdx.x, ty = threadIdx.y;
#pragma unroll
    for (int j = 0; j < 4; j++) {
        int k = k0 + ty + j * 8;
        int n = n0 + tx;
        float v = 0.f;
        if (n < 16) v = shared_w1[k * RANK + n];
        else if (n < 112) {
            int jj = n - 16, e = jj >> 4, r = jj & 15;
            v = routed_w1[(size_t)e * DIN * RANK + k * RANK + r];
        }
        tile[ty + j * 8][tx] = f2bf(v);
    }
    __syncthreads();
#pragma unroll
    for (int j = 0; j < 4; j++) {
        int n = n0 + ty + j * 8;
        int k = k0 + tx;
        W1T[(size_t)n * DIN + k] = tile[tx][ty + j * 8];
    }
}

// Per 8-token block: convert x -> bf16 into A[:, 0:1280] (vectorized 8-wide),
// zero A[:, 1392:1408], fp32 router logits -> softmax -> top-3 -> cw[T,6].
__global__ __launch_bounds__(256) void router_kernel(
    const float* __restrict__ x,
    const float* __restrict__ router_w,
    const float* __restrict__ router_b,
    unsigned short* __restrict__ A,
    float* __restrict__ cw) {
    int tid = threadIdx.x;
    size_t t0 = (size_t)blockIdx.x * 8;
    const float* xblk = x + t0 * DIN;
    unsigned short* Ablk = A + t0 * KPAD;

    for (int i = tid; i < 8 * (DIN / 8); i += 256) {
        int t = i / (DIN / 8), c = (i - t * (DIN / 8)) * 8;
        const float* xs = xblk + (size_t)t * DIN + c;
        f32x4 v0 = *(const f32x4*)xs;
        f32x4 v1 = *(const f32x4*)(xs + 4);
        u16x8 o;
#pragma unroll
        for (int j = 0; j < 4; j++) { o[j] = f2bf(v0[j]); o[4 + j] = f2bf(v1[j]); }
        *(u16x8*)&Ablk[(size_t)t * KPAD + c] = o;
    }
    if (tid < 128) {
        int t = tid >> 4, c = tid & 15;
        Ablk[t * KPAD + DIN + 112 + c] = 0;
    }

    int tg = tid >> 5, lj = tid & 31;
    const float* xt = xblk + (size_t)tg * DIN;
    float acc[6] = {0.f, 0.f, 0.f, 0.f, 0.f, 0.f};
    for (int k = lj; k < DIN; k += 32) {
        float xv = xt[k];
        const float* wr = router_w + k * NEXP;
#pragma unroll
        for (int e = 0; e < NEXP; e++) acc[e] = fmaf(xv, wr[e], acc[e]);
    }
#pragma unroll
    for (int off = 16; off > 0; off >>= 1)
#pragma unroll
        for (int e = 0; e < NEXP; e++) acc[e] += __shfl_xor(acc[e], off);

    float mx = -1e30f;
#pragma unroll
    for (int e = 0; e < NEXP; e++) { acc[e] += router_b[e]; mx = fmaxf(mx, acc[e]); }
    float g[6]; float s = 0.f;
#pragma unroll
    for (int e = 0; e < NEXP; e++) { g[e] = __expf(acc[e] - mx); s += g[e]; }
    float inv = 1.f / s;
    if (lj < NEXP) {
        float ge = g[lj];
        int cnt = 0;
#pragma unroll
        for (int e = 0; e < NEXP; e++) {
            if (e == lj) continue;
            if (g[e] > ge || (g[e] == ge && e < lj)) cnt++;  // tie -> lowest index wins
        }
        cw[(t0 + tg) * NEXP + lj] = (cnt < 3) ? ge * inv : 0.f;
    }
}

// A[t, 1280+j] = bf16( (j<16 ? 1 : cw[t][(j-16)/16]) * (H0+H1)[t][j] ), j in [0,112)
__global__ __launch_bounds__(256) void combine_kernel(
    const float* __restrict__ H, const float* __restrict__ cw,
    unsigned short* __restrict__ A) {
    int i = blockIdx.x * 256 + threadIdx.x;  // < TOKENS*112
    int t = i / 112, j = i - t * 112;
    float h = H[(size_t)t * NLOW + j] + H[(size_t)TOKENS * NLOW + (size_t)t * NLOW + j];
    float f = (j < 16) ? 1.0f : cw[t * NEXP + ((j - 16) >> 4)];
    A[(size_t)t * KPAD + DIN + j] = f2bf(f * h);
}

// Small GEMM H[z][m,n] = A[m, z*640 : z*640+640] @ W1T[n, z*640 : ...]^T.
__global__ __launch_bounds__(256, 2) void gemm_small(
    const unsigned short* __restrict__ A,
    const unsigned short* __restrict__ BT,
    float* __restrict__ H) {
    __shared__ unsigned short ldsA[128 * 32];
    __shared__ unsigned short ldsB[128 * 32];
    const int KS = DIN / 2;  // 640
    int tid = threadIdx.x;
    int lane = tid & 63, wave = tid >> 6;
    int m0 = blockIdx.y * 128;
    int z = blockIdx.z;
    int wm = (wave >> 1) * 64, wn = (wave & 1) * 64;
    int lr = lane & 15, quad = lane >> 4;

    f32x4 acc[4][4] = {};
    const unsigned short* Abase = A + (size_t)m0 * KPAD + z * KS;
    const unsigned short* Bbase = BT + z * KS;
    float* Cbase = H + (size_t)z * TOKENS * NLOW;

    for (int k0 = 0; k0 < KS; k0 += 32) {
#pragma unroll
        for (int i = 0; i < 2; i++) {
            int c = i * 256 + tid;
            int row = c >> 2;
            int col = (c & 3) << 3;
            async_load16(&ldsA[(i * 256 + wave * 64) * 8],
                         Abase + (size_t)row * KPAD + k0 + col);
            async_load16(&ldsB[(i * 256 + wave * 64) * 8],
                         Bbase + (size_t)row * DIN + k0 + col);
        }
        __syncthreads();
        bf16x8 af[4], bf[4];
#pragma unroll
        for (int mi = 0; mi < 4; mi++)
            af[mi] = *(const bf16x8*)&ldsA[(wm + mi * 16 + lr) * 32 + quad * 8];
#pragma unroll
        for (int ni = 0; ni < 4; ni++)
            bf[ni] = *(const bf16x8*)&ldsB[(wn + ni * 16 + lr) * 32 + quad * 8];
#pragma unroll
        for (int mi = 0; mi < 4; mi++)
#pragma unroll
            for (int ni = 0; ni < 4; ni++)
                acc[mi][ni] = __builtin_amdgcn_mfma_f32_16x16x32_bf16(
                    af[mi], bf[ni], acc[mi][ni], 0, 0, 0);
        __syncthreads();
    }
#pragma unroll
    for (int ni = 0; ni < 4; ni++) {
        int gn = wn + ni * 16 + lr;
#pragma unroll
        for (int mi = 0; mi < 4; mi++) {
            int gm = m0 + wm + mi * 16 + quad * 4;
            f32x4 v = acc[mi][ni];
#pragma unroll
            for (int r = 0; r < 4; r++)
                Cbase[(size_t)(gm + r) * NLOW + gn] = v[r];
        }
    }
}

// ---------- big GEMM: 256x128 tile, BK=32, 512 thr, 2 blocks/CU (m114 TLP) ----------
// R4 ablation: MFMA+sync skeleton = 84.5% util; all intra-block schedules pin at 33%.
// -> stop fighting intra-block overlap; use cross-block overlap (m114: independent
// blocks' MFMA and memory phases interleave on the CU). 48 KB LDS + <=128 unified
// regs/wave -> 2 blocks/CU via __launch_bounds__(512,4). One __syncthreads per
// K-tile (compiler-managed waits); stage(t+1) issued right after it.
// LDS swizzle: source chunk c ^= (row>>1)&3 -> frag reads hit all 8 (parity,chunk)
// bank groups, exactly 2 lanes/bank = free (m136).

#define BM 256
#define BN 128
#define BKS 32

__global__ __launch_bounds__(512, 4) void gemm256(
    const unsigned short* __restrict__ A,
    const unsigned short* __restrict__ BT,
    const float* __restrict__ bias,
    float* __restrict__ C) {
    __shared__ unsigned short lA[2][BM * BKS];   // 2 x 16 KB
    __shared__ unsigned short lB[2][BN * BKS];   // 2 x 8 KB   -> 48 KB total

    int tid = threadIdx.x;
    int lane = tid & 63, wave = tid >> 6;
    int bid = blockIdx.x;
    // XCD swizzle (1920 % 8 == 0, bijective): XCD x owns m-tiles [8x, 8x+8);
    // 8 consecutive blocks share one 352 KB B-panel in their XCD's L2.
    int xcd = bid & 7, lid = bid >> 3;
    int mt = xcd * 8 + (lid & 7);   // 0..63
    int nt = lid >> 3;              // 0..29
    int m0 = mt * BM, n0 = nt * BN;

    int wm = (wave >> 1) * 64, wn = (wave & 1) * 64;   // 4M x 2N waves, 64x64 each
    int lr = lane & 15, quad = lane >> 4;

    // Staging: thread t writes LDS 16B chunk at (row = t>>2 [+128], chunk = t&3),
    // linear dest (gload_lds requirement); source takes chunk (t&3) ^ ((t>>3)&3)
    // [= c ^ ((row>>1)&3)], the same involution the reads apply.
    int srow = tid >> 2;                      // 0..127
    int scg = (tid & 3) ^ ((tid >> 3) & 3);   // pre-swizzled source chunk
    const unsigned short* aSrc = A + (size_t)(m0 + srow) * KPAD + scg * 8;
    const unsigned short* bSrc = BT + (size_t)(n0 + srow) * KPAD + scg * 8;

    f32x4 acc[4][4] = {};

    const int nkt = KPAD / BKS;  // 44
    // prologue: stage tile 0
    {
        async_load16(&lA[0][0] + (size_t)tid * 8, aSrc);
        async_load16(&lA[0][0] + 128 * BKS + (size_t)tid * 8, aSrc + (size_t)128 * KPAD);
        async_load16(&lB[0][0] + (size_t)tid * 8, bSrc);
    }

#pragma unroll 2
    for (int t = 0; t < nkt; ++t) {
        __syncthreads();   // stage(t) resident (vm drain); prev tile's reads retired
        if (t + 1 < nkt) {
            int k1 = (t + 1) * BKS;
            unsigned short* dA = &lA[(t + 1) & 1][0];
            unsigned short* dB = &lB[(t + 1) & 1][0];
            async_load16(dA + (size_t)tid * 8, aSrc + k1);
            async_load16(dA + 128 * BKS + (size_t)tid * 8, aSrc + (size_t)128 * KPAD + k1);
            async_load16(dB + (size_t)tid * 8, bSrc + k1);
        }
        const unsigned short* a_cur = &lA[t & 1][0];
        const unsigned short* b_cur = &lB[t & 1][0];
        bf16x8 af[4], bf[4];
#pragma unroll
        for (int mi = 0; mi < 4; mi++) {
            int row = wm + mi * 16 + lr;
            int off = row * 64 + (((quad ^ ((row >> 1) & 3))) << 4);  // bytes
            af[mi] = *(const bf16x8*)((const char*)a_cur + off);
        }
#pragma unroll
        for (int ni = 0; ni < 4; ni++) {
            int row = wn + ni * 16 + lr;
            int off = row * 64 + (((quad ^ ((row >> 1) & 3))) << 4);
            bf[ni] = *(const bf16x8*)((const char*)b_cur + off);
        }
#pragma unroll
        for (int mi = 0; mi < 4; mi++)
#pragma unroll
            for (int ni = 0; ni < 4; ni++)
                acc[mi][ni] = __builtin_amdgcn_mfma_f32_16x16x32_bf16(
                    af[mi], bf[ni], acc[mi][ni], 0, 0, 0);
    }

    // Epilogue: C/D layout col = lane&15, row = quad*4 + reg (verified mapping)
#pragma unroll
    for (int mi = 0; mi < 4; mi++) {
        int gm = m0 + wm + mi * 16 + quad * 4;
#pragma unroll
        for (int ni = 0; ni < 4; ni++) {
            int gn = n0 + wn + ni * 16 + lr;
            float bv = bias[gn];
            f32x4 v = acc[mi][ni];
#pragma unroll
            for (int r = 0; r < 4; r++)
                C[(size_t)(gm + r) * DOUT + gn] = v[r] + bv;
        }
    }
}

extern "C" void kernel_launch(void* const* d_in, const int* in_sizes, int n_in,
                              void* d_out, int out_size, void* d_ws, size_t ws_size,
                              hipStream_t stream) {
    const float* x         = (const float*)d_in[0];
    const float* base_w    = (const float*)d_in[1];
    const float* base_b    = (const float*)d_in[2];
    const float* shared_w1 = (const float*)d_in[3];
    const float* shared_w2 = (const float*)d_in[4];
    const float* routed_w1 = (const float*)d_in[5];
    const float* routed_w2 = (const float*)d_in[6];
    const float* router_w  = (const float*)d_in[7];
    const float* router_b  = (const float*)d_in[8];
    float* out = (float*)d_out;

    char* ws = (char*)d_ws;
    size_t off = 0;
    unsigned short* A     = (unsigned short*)(ws + off); off += (size_t)TOKENS * KPAD * 2;
    unsigned short* WcatT = (unsigned short*)(ws + off); off += (size_t)DOUT * KPAD * 2;
    unsigned short* W1T   = (unsigned short*)(ws + off); off += (size_t)NLOW * DIN * 2;
    float* H              = (float*)(ws + off);          off += (size_t)2 * TOKENS * NLOW * 4;
    float* cw             = (float*)(ws + off);          off += (size_t)TOKENS * NEXP * 4;

    prep_w2t<<<dim3(KPAD / 32, DOUT / 32), dim3(32, 8), 0, stream>>>(
        base_w, shared_w2, routed_w2, WcatT);
    prep_w1t<<<dim3(DIN / 32, NLOW / 32), dim3(32, 8), 0, stream>>>(
        shared_w1, routed_w1, W1T);
    router_kernel<<<TOKENS / 8, 256, 0, stream>>>(x, router_w, router_b, A, cw);
    gemm_small<<<dim3(1, TOKENS / 128, 2), 256, 0, stream>>>(A, W1T, H);
    combine_kernel<<<(TOKENS * 112) / 256, 256, 0, stream>>>(H, cw, A);
    gemm256<<<(DOUT / BN) * (TOKENS / BM), 512, 0, stream>>>(
        A, WcatT, base_b, out);
}